// Round 9
// baseline (283.178 us; speedup 1.0000x reference)
//
#include <hip/hip_runtime.h>
#include <math.h>

#define BB 64
#define TT 2048
#define DD 512
#define NCH 16            // PV chunks per b: 1024 blocks x 128 rows (round-3 proven shape)
#define TC (TT / NCH)     // 128 rows per chunk

// Monotone float<->uint mapping: u-order == float-order; u=0 sorts below -inf.
__device__ __forceinline__ unsigned fenc(float f) {
  unsigned b = __float_as_uint(f);
  return (b & 0x80000000u) ? ~b : (b | 0x80000000u);
}
__device__ __forceinline__ float fdec(unsigned u) {
  return __uint_as_float((u & 0x80000000u) ? (u & 0x7FFFFFFFu) : ~u);
}

// ---------------------------------------------------------------------------
// Kernel 1: energy[b,t] = dot(key[b,t,:], query[b,:]); masked -> -inf.
// 256 threads = 4 waves; wave computes one row (proven ~6.7 TB/s shape).
// NEW: block-level max -> one exact atomicMax per block into mslot[b]
// (bitwise max on monotone uints: order-independent => deterministic).
// ---------------------------------------------------------------------------
__global__ __launch_bounds__(256) void energy_kernel(
    const float* __restrict__ q, const float* __restrict__ k,
    const int* __restrict__ mask, float* __restrict__ energy,
    unsigned* __restrict__ mslot) {
  const int wave = threadIdx.x >> 6;
  const int lane = threadIdx.x & 63;
  const long long row = (long long)blockIdx.x * 4 + wave;  // b*TT + t
  const int b = (int)(row >> 11);                          // same b for all 4 waves

  __shared__ float smax[4];

  const float4* kp4 = (const float4*)(k + row * DD);
  const float4* qp4 = (const float4*)(q + (long long)b * DD);

  float4 ka = kp4[lane];
  float4 kb = kp4[lane + 64];
  float4 qa = qp4[lane];
  float4 qb = qp4[lane + 64];

  float s = ka.x * qa.x + ka.y * qa.y + ka.z * qa.z + ka.w * qa.w +
            kb.x * qb.x + kb.y * qb.y + kb.z * qb.z + kb.w * qb.w;

#pragma unroll
  for (int off = 32; off; off >>= 1) s += __shfl_down(s, off, 64);

  if (lane == 0) {
    const float e = mask[row] ? -INFINITY : s;
    energy[row] = e;
    smax[wave] = e;
  }
  __syncthreads();
  if (threadIdx.x == 0) {
    const float mb = fmaxf(fmaxf(smax[0], smax[1]), fmaxf(smax[2], smax[3]));
    atomicMax(&mslot[b], fenc(mb));
  }
}

// ---------------------------------------------------------------------------
// Kernel 2: slim PV. Grid (BB, NCH) x 128 threads, 128 rows per block.
// Prologue is now tiny: m (4B) + own 128 energies (512B) + 1 expf + 1 barrier.
// Writes unnormalized weights (wbuf), chunk sum (sstat), V-chunk partial.
// No cross-block comm. Stream shape identical to round-3 best.
// ---------------------------------------------------------------------------
__global__ __launch_bounds__(128) void pv_slim(
    const float* __restrict__ energy, const float* __restrict__ v,
    const unsigned* __restrict__ mslot,
    float* __restrict__ wbuf, float* __restrict__ partial,
    float* __restrict__ sstat) {
  const int b = blockIdx.x;
  const int c = blockIdx.y;
  const int tid = threadIdx.x;  // 0..127
  const int wave = tid >> 6;
  const int lane = tid & 63;

  __shared__ float sa[TC];
  __shared__ float sws[2];

  const unsigned mu = mslot[b];
  const float m = (mu == 0u) ? 0.f : fdec(mu);  // all-masked guard

  // weights for this block's 128 rows (coalesced 512B read)
  const float e = energy[b * TT + c * TC + tid];
  const float w = __expf(e - m);  // e = -inf -> 0
  sa[tid] = w;
  wbuf[b * TT + c * TC + tid] = w;

  float ws_ = w;
#pragma unroll
  for (int off = 32; off; off >>= 1) ws_ += __shfl_xor(ws_, off, 64);
  if (lane == 0) sws[wave] = ws_;
  __syncthreads();
  if (tid == 0) sstat[b * NCH + c] = sws[0] + sws[1];

  // V stream: thread owns float4 at d = 4*tid; a[t] is an LDS broadcast
  const float4* vp = (const float4*)(v + ((long long)b * TT + c * TC) * DD);
  float4 acc = {0.f, 0.f, 0.f, 0.f};
#pragma unroll 8
  for (int t = 0; t < TC; t++) {
    const float a = sa[t];
    const float4 vv = vp[t * 128 + tid];
    acc.x += a * vv.x;
    acc.y += a * vv.y;
    acc.z += a * vv.z;
    acc.w += a * vv.w;
  }
  ((float4*)partial)[(b * NCH + c) * 128 + tid] = acc;
}

// ---------------------------------------------------------------------------
// Kernel 3: finalize per b: S = sum of 16 chunk sums (fixed order), then
// ctx = inv * sum of 16 partials (4MB L2) and attn = wbuf * inv (512KB L2).
// One block (256 thr) per b.
// ---------------------------------------------------------------------------
__global__ __launch_bounds__(256) void finalize(
    const float* __restrict__ wbuf, const float* __restrict__ partial,
    const float* __restrict__ sstat,
    float* __restrict__ ctx, float* __restrict__ attn) {
  const int b = blockIdx.x;
  const int tid = threadIdx.x;
  const int lane = tid & 63;

  __shared__ float sinv;

  if (tid < 64) {
    float s = (lane < NCH) ? sstat[b * NCH + lane] : 0.f;
    s += __shfl_xor(s, 8, 64);
    s += __shfl_xor(s, 4, 64);
    s += __shfl_xor(s, 2, 64);
    s += __shfl_xor(s, 1, 64);
    if (lane == 0) sinv = 1.0f / s;
  }
  __syncthreads();
  const float inv = sinv;

  // context: thread owns float2 at d2 = tid
  const float2* p2 = (const float2*)partial;
  float2 a = {0.f, 0.f};
#pragma unroll
  for (int c = 0; c < NCH; c++) {
    const float2 p = p2[(b * NCH + c) * 256 + tid];
    a.x += p.x;
    a.y += p.y;
  }
  float2 o;
  o.x = a.x * inv;
  o.y = a.y * inv;
  ((float2*)ctx)[b * 256 + tid] = o;

  // attention row: 2048 floats, 2 float4 per thread
  const float4* w4 = (const float4*)(wbuf + b * TT);
  float4* a4 = (float4*)(attn + b * TT);
#pragma unroll
  for (int i = 0; i < 2; i++) {
    const int idx = i * 256 + tid;
    const float4 w = w4[idx];
    float4 ao;
    ao.x = w.x * inv; ao.y = w.y * inv; ao.z = w.z * inv; ao.w = w.w * inv;
    a4[idx] = ao;
  }
}

// ---------------------------------------------------------------------------
extern "C" void kernel_launch(void* const* d_in, const int* in_sizes, int n_in,
                              void* d_out, int out_size, void* d_ws, size_t ws_size,
                              hipStream_t stream) {
  const float* q    = (const float*)d_in[0];  // [B,D]
  const float* k    = (const float*)d_in[1];  // [B,T,D]
  const float* v    = (const float*)d_in[2];  // [B,T,D]
  const int*   mask = (const int*)d_in[3];    // [B,T], 0/1

  float* out  = (float*)d_out;
  float* ctx  = out;            // [B,D]   first output
  float* attn = out + BB * DD;  // [B,T]   second output

  float*    energy  = (float*)d_ws;              // B*T           = 512 KB
  float*    wbuf    = energy + BB * TT;          // B*T           = 512 KB
  float*    partial = wbuf + BB * TT;            // B*NCH*D       = 4 MB
  float*    sstat   = partial + BB * NCH * DD;   // B*NCH         = 4 KB
  unsigned* mslot   = (unsigned*)(sstat + BB * NCH);  // 64 u32   = 256 B

  hipMemsetAsync(mslot, 0, BB * sizeof(unsigned), stream);
  energy_kernel<<<BB * TT / 4, 256, 0, stream>>>(q, k, mask, energy, mslot);
  pv_slim<<<dim3(BB, NCH), 128, 0, stream>>>(energy, v, mslot, wbuf, partial, sstat);
  finalize<<<BB, 256, 0, stream>>>(wbuf, partial, sstat, ctx, attn);
}

// Round 10
// 102.553 us; speedup vs baseline: 2.7613x; 2.7613x over previous
//
#include <hip/hip_runtime.h>
#include <math.h>

#define BB 64
#define TT 2048
#define DD 512
#define NCH 16            // PV chunks per b: 1024 blocks x 128 rows (proven shape)
#define TC (TT / NCH)     // 128 rows per chunk

// ---------------------------------------------------------------------------
// Kernel 1: energy[b,t] = dot(key[b,t,:], query[b,:]); masked -> -inf.
// 256 threads = 4 waves; each wave one row. Proven ~6.7 TB/s (r1/3/7/8).
// NO atomics, NO extra barriers (round-9: hot-line atomicMax = 226us).
// ---------------------------------------------------------------------------
__global__ __launch_bounds__(256) void energy_kernel(
    const float* __restrict__ q, const float* __restrict__ k,
    const int* __restrict__ mask, float* __restrict__ energy) {
  const int wave = threadIdx.x >> 6;
  const int lane = threadIdx.x & 63;
  const long long row = (long long)blockIdx.x * 4 + wave;  // b*TT + t
  const int b = (int)(row >> 11);

  const float4* kp4 = (const float4*)(k + row * DD);
  const float4* qp4 = (const float4*)(q + (long long)b * DD);

  float4 ka = kp4[lane];
  float4 kb = kp4[lane + 64];
  float4 qa = qp4[lane];
  float4 qb = qp4[lane + 64];

  float s = ka.x * qa.x + ka.y * qa.y + ka.z * qa.z + ka.w * qa.w +
            kb.x * qb.x + kb.y * qb.y + kb.z * qb.z + kb.w * qb.w;

#pragma unroll
  for (int off = 32; off; off >>= 1) s += __shfl_down(s, off, 64);

  if (lane == 0) {
    energy[row] = mask[row] ? -INFINITY : s;
  }
}

// ---------------------------------------------------------------------------
// Kernel 2: row softmax over T for each b. One block (256 thr) per b.
// Writes normalized attention straight into d_out (proven round-1 shape).
// ---------------------------------------------------------------------------
__global__ __launch_bounds__(256) void softmax_kernel(
    const float* __restrict__ energy, float* __restrict__ attn) {
  const int b = blockIdx.x;
  const int tid = threadIdx.x;
  const int wave = tid >> 6;
  const int lane = tid & 63;

  float vals[8];
  float m = -INFINITY;
#pragma unroll
  for (int i = 0; i < 8; i++) {
    vals[i] = energy[b * TT + i * 256 + tid];
    m = fmaxf(m, vals[i]);
  }
#pragma unroll
  for (int off = 32; off; off >>= 1) m = fmaxf(m, __shfl_xor(m, off, 64));

  __shared__ float sm[4];
  __shared__ float ss[4];
  if (lane == 0) sm[wave] = m;
  __syncthreads();
  m = fmaxf(fmaxf(sm[0], sm[1]), fmaxf(sm[2], sm[3]));

  float ssum = 0.f;
#pragma unroll
  for (int i = 0; i < 8; i++) {
    vals[i] = __expf(vals[i] - m);  // exp(-inf) = 0 for masked slots
    ssum += vals[i];
  }
#pragma unroll
  for (int off = 32; off; off >>= 1) ssum += __shfl_xor(ssum, off, 64);
  if (lane == 0) ss[wave] = ssum;
  __syncthreads();
  ssum = ss[0] + ss[1] + ss[2] + ss[3];

  const float inv = 1.0f / ssum;
#pragma unroll
  for (int i = 0; i < 8; i++) {
    attn[b * TT + i * 256 + tid] = vals[i] * inv;
  }
}

// ---------------------------------------------------------------------------
// Kernel 3: slim PV. Grid (BB, NCH) x 128 threads, 128 rows per block.
// Prologue: ONE coalesced 512B read of this block's normalized weights into
// LDS + one barrier. No expf, no reductions, no row re-read (round-3's
// heavy per-block softmax prologue cost ~4us across 1024 blocks).
// Stream: thread owns float4 at d=4*tid; weight is an LDS broadcast.
// ---------------------------------------------------------------------------
__global__ __launch_bounds__(128) void pv_slim(
    const float* __restrict__ attn, const float* __restrict__ v,
    float* __restrict__ partial) {
  const int b = blockIdx.x;
  const int c = blockIdx.y;
  const int tid = threadIdx.x;  // 0..127

  __shared__ float sa[TC];
  sa[tid] = attn[b * TT + c * TC + tid];
  __syncthreads();

  const float4* vp = (const float4*)(v + ((long long)b * TT + (long long)c * TC) * DD);
  float4 acc = {0.f, 0.f, 0.f, 0.f};
#pragma unroll 8
  for (int t = 0; t < TC; t++) {
    const float a = sa[t];
    const float4 vv = vp[t * 128 + tid];
    acc.x += a * vv.x;
    acc.y += a * vv.y;
    acc.z += a * vv.z;
    acc.w += a * vv.w;
  }
  ((float4*)partial)[(b * NCH + c) * 128 + tid] = acc;
}

// ---------------------------------------------------------------------------
// Kernel 4: context[b,d] = sum over 16 partials (2 MB, L2-resident).
// One thread per float4 of context: B*D/4 = 8192 threads = 32 blocks.
// ---------------------------------------------------------------------------
__global__ __launch_bounds__(256) void pv_reduce(
    const float* __restrict__ partial, float* __restrict__ ctx) {
  const int i = blockIdx.x * 256 + threadIdx.x;  // over B*128 float4s
  const int b = i >> 7;
  const int d4 = i & 127;
  const float4* p4 = (const float4*)partial;
  float4 s = {0.f, 0.f, 0.f, 0.f};
#pragma unroll
  for (int c = 0; c < NCH; c++) {
    const float4 p = p4[(b * NCH + c) * 128 + d4];
    s.x += p.x; s.y += p.y; s.z += p.z; s.w += p.w;
  }
  ((float4*)ctx)[i] = s;
}

// ---------------------------------------------------------------------------
extern "C" void kernel_launch(void* const* d_in, const int* in_sizes, int n_in,
                              void* d_out, int out_size, void* d_ws, size_t ws_size,
                              hipStream_t stream) {
  const float* q    = (const float*)d_in[0];  // [B,D]
  const float* k    = (const float*)d_in[1];  // [B,T,D]
  const float* v    = (const float*)d_in[2];  // [B,T,D]
  const int*   mask = (const int*)d_in[3];    // [B,T], 0/1

  float* out  = (float*)d_out;
  float* ctx  = out;            // [B,D]   first output
  float* attn = out + BB * DD;  // [B,T]   second output

  float* energy  = (float*)d_ws;        // B*T floats   = 512 KB
  float* partial = energy + BB * TT;    // B*NCH*D fl   = 2 MB

  energy_kernel<<<BB * TT / 4, 256, 0, stream>>>(q, k, mask, energy);
  softmax_kernel<<<BB, 256, 0, stream>>>(energy, attn);
  pv_slim<<<dim3(BB, NCH), 128, 0, stream>>>(attn, v, partial);
  pv_reduce<<<BB * DD / 4 / 256, 256, 0, stream>>>(partial, ctx);
}